// Round 8
// baseline (326.340 us; speedup 1.0000x reference)
//
#include <hip/hip_runtime.h>
#include <stdint.h>

#define TTOK 4096
#define DM   1024
#define FF   2048
#define NE   8
#define SHSEG 10240          // fixed base of shared-expert rows in H (max padded routed = 10240)
#define HROWS 14336          // SHSEG + TTOK

typedef __attribute__((ext_vector_type(8))) short short8;
typedef __attribute__((ext_vector_type(8))) unsigned short ushort8;
typedef __attribute__((ext_vector_type(4))) float f32x4;

// ---------------- workspace layout (bytes) ----------------
#define OFF_XB      0ull
#define OFF_WB13    (OFF_XB      + (size_t)TTOK*DM*2)
#define OFF_WB2     (OFF_WB13    + (size_t)9*4096*1024*2)
#define OFF_H       (OFF_WB2     + (size_t)9*1024*2048*2)
#define OFF_CONTRIB OFF_WB13     // overlay: wb13 dead after g13; contrib 40MB < wb13 75MB
#define OFF_TOPKW   (OFF_H       + (size_t)HROWS*2048*2)
#define OFF_TOPKI   (OFF_TOPKW   + (size_t)TTOK*2*4)
#define OFF_SLOTTOK (OFF_TOPKI   + (size_t)TTOK*2*4)
#define OFF_TOKSLOT (OFF_SLOTTOK + (size_t)SHSEG*4)
#define OFF_OFFS    (OFF_TOKSLOT + (size_t)TTOK*2*4)
#define WS_NEEDED   (OFF_OFFS + 64)

#define VMWAIT(N) asm volatile("s_waitcnt vmcnt(" #N ")" ::: "memory")
#define LGKM0()   asm volatile("s_waitcnt lgkmcnt(0)" ::: "memory")
#define BAR()     __builtin_amdgcn_s_barrier()
#define SCHED0()  __builtin_amdgcn_sched_barrier(0)

__device__ __forceinline__ unsigned short f2bf(float f) {
  unsigned u = __float_as_uint(f);
  return (unsigned short)((u + 0x7FFFu + ((u >> 16) & 1u)) >> 16);
}

__device__ __forceinline__ void async16(const void* g, void* l) {
  __builtin_amdgcn_global_load_lds(
      (const __attribute__((address_space(1))) void*)g,
      (__attribute__((address_space(3))) void*)l, 16, 0, 0);
}

// ---------------- gate (fp32) + x->bf16 convert ----------------
__global__ void k_gatecvt(const float* __restrict__ x, const float* __restrict__ Wg,
                          float* __restrict__ topkw, int* __restrict__ topki,
                          unsigned short* __restrict__ xb) {
  int wave = threadIdx.x >> 6;
  int lane = threadIdx.x & 63;
  int t = blockIdx.x * 4 + wave;
  float acc[NE];
#pragma unroll
  for (int e = 0; e < NE; e++) acc[e] = 0.f;
  const float* xr = x + (size_t)t * DM;
  unsigned short* xbr = xb + (size_t)t * DM;
#pragma unroll
  for (int i = 0; i < 4; i++) {
    int k = i * 256 + lane * 4;
    f32x4 xv = *(const f32x4*)(xr + k);
    unsigned short o0 = f2bf(xv[0]), o1 = f2bf(xv[1]), o2 = f2bf(xv[2]), o3 = f2bf(xv[3]);
    unsigned long long pk = (unsigned long long)o0 | ((unsigned long long)o1 << 16) |
                            ((unsigned long long)o2 << 32) | ((unsigned long long)o3 << 48);
    *(unsigned long long*)(xbr + k) = pk;
#pragma unroll
    for (int j = 0; j < 4; j++) {
      const float* wr = Wg + (size_t)(k + j) * NE;
#pragma unroll
      for (int e = 0; e < NE; e++) acc[e] += xv[j] * wr[e];
    }
  }
#pragma unroll
  for (int e = 0; e < NE; e++) {
#pragma unroll
    for (int off = 32; off >= 1; off >>= 1) acc[e] += __shfl_xor(acc[e], off, 64);
  }
  if (lane == 0) {
    float g[NE];
#pragma unroll
    for (int e = 0; e < NE; e++) g[e] = 1.f / (1.f + __expf(-acc[e]));
    int i1 = -1, i2 = -1;
    float m1 = -1e30f, m2 = -1e30f;
#pragma unroll
    for (int e = 0; e < NE; e++) {
      float v = g[e];
      if (v > m1) { m2 = m1; i2 = i1; m1 = v; i1 = e; }
      else if (v > m2) { m2 = v; i2 = e; }
    }
    float s = m1 + m2;
    topkw[t * 2 + 0] = m1 / s;
    topkw[t * 2 + 1] = m2 / s;
    topki[t * 2 + 0] = i1;
    topki[t * 2 + 1] = i2;
  }
}

// single block: count, 256-aligned prefix, scatter; offs_g[8] = padded total
__global__ void k_route(const int* __restrict__ topki, int* __restrict__ offs_g,
                        int* __restrict__ slot_token, int* __restrict__ token_slot) {
  __shared__ int cnt[NE], off[NE], fill[NE];
  int tid = threadIdx.x;
  if (tid < NE) { cnt[tid] = 0; fill[tid] = 0; }
  __syncthreads();
  for (int t = tid; t < TTOK; t += 1024) {
    atomicAdd(&cnt[topki[t * 2 + 0]], 1);
    atomicAdd(&cnt[topki[t * 2 + 1]], 1);
  }
  __syncthreads();
  if (tid == 0) {
    int s = 0;
    for (int e = 0; e < NE; e++) { off[e] = s; s += (cnt[e] + 255) & ~255; }
    offs_g[8] = s;
  }
  __syncthreads();
  if (tid < NE) offs_g[tid] = off[tid];
  for (int s = tid; s < SHSEG; s += 1024) slot_token[s] = 0;   // pad slots -> token 0
  __syncthreads();
  for (int t = tid; t < TTOK; t += 1024) {
#pragma unroll
    for (int k = 0; k < 2; k++) {
      int e = topki[t * 2 + k];
      int pos = atomicAdd(&fill[e], 1);
      int slot = off[e] + pos;
      slot_token[slot] = t;
      token_slot[t * 2 + k] = slot;
    }
  }
}

// ---------------- vectorized 64x64 transposes ----------------
__global__ void k_t13(const float* __restrict__ We1, const float* __restrict__ We3,
                      const float* __restrict__ Ws1, const float* __restrict__ Ws3,
                      unsigned short* __restrict__ wb13) {
  __shared__ float tile[64][68];
  int z = blockIdx.z;
  unsigned short* dst = wb13 + (size_t)z * 4096 * 1024;
  int r0 = blockIdx.y * 64;
  int c0 = blockIdx.x * 64;
  int tid = threadIdx.x;
  int r = tid >> 2, q = tid & 3;
  int nn = tid >> 2, g = tid & 3;

  const float* srcs[2] = {(blockIdx.z < 8) ? We1 + (size_t)z * DM * FF : Ws1,
                          (blockIdx.z < 8) ? We3 + (size_t)z * DM * FF : Ws3};
#pragma unroll
  for (int m = 0; m < 2; m++) {
    const float* src = srcs[m] + (size_t)(r0 + r) * FF + c0;
#pragma unroll
    for (int i = 0; i < 4; i++)
      *(f32x4*)&tile[r][i * 16 + q * 4] = *(const f32x4*)(src + i * 16 + q * 4);
    __syncthreads();
    int n = c0 + nn;
    int d = ((n >> 4) << 5) + (n & 15) + m * 16;
    ushort8 o0, o1;
#pragma unroll
    for (int j = 0; j < 8; j++) o0[j] = f2bf(tile[g * 16 + j][nn]);
#pragma unroll
    for (int j = 0; j < 8; j++) o1[j] = f2bf(tile[g * 16 + 8 + j][nn]);
    unsigned short* dp = dst + (size_t)d * 1024 + r0 + g * 16;
    *(ushort8*)dp = o0;
    *(ushort8*)(dp + 8) = o1;
    __syncthreads();
  }
}

__global__ void k_t2(const float* __restrict__ We2, const float* __restrict__ Ws2,
                     unsigned short* __restrict__ wb2) {
  __shared__ float tile[64][68];
  int z = blockIdx.z;
  const float* src0 = (z < 8) ? We2 + (size_t)z * FF * DM : Ws2;
  unsigned short* dst = wb2 + (size_t)z * 1024 * 2048;
  int r0 = blockIdx.y * 64;
  int c0 = blockIdx.x * 64;
  int tid = threadIdx.x;
  int r = tid >> 2, q = tid & 3;
  int nn = tid >> 2, g = tid & 3;

  const float* src = src0 + (size_t)(r0 + r) * DM + c0;
#pragma unroll
  for (int i = 0; i < 4; i++)
    *(f32x4*)&tile[r][i * 16 + q * 4] = *(const f32x4*)(src + i * 16 + q * 4);
  __syncthreads();
  ushort8 o0, o1;
#pragma unroll
  for (int j = 0; j < 8; j++) o0[j] = f2bf(tile[g * 16 + j][nn]);
#pragma unroll
  for (int j = 0; j < 8; j++) o1[j] = f2bf(tile[g * 16 + 8 + j][nn]);
  unsigned short* dp = dst + (size_t)(c0 + nn) * 2048 + r0 + g * 16;
  *(ushort8*)dp = o0;
  *(ushort8*)(dp + 8) = o1;
}

// ---------------- 256x256 8-phase GEMM, BK=64, vmcnt(6) calendar, XCD my-group swizzle ----
// Grid is 1D (56*NB blocks). Bijective remap: wg = (bid%8)*(TOT/8) + bid/8 puts 7 contiguous
// my's x NB bn on each XCD (bn fastest => the NB blocks sharing one A-tile hit the same L2).
// Serpentine bn per my => adjacent same-expert my's reuse trailing B-tiles in L2.
// Stage units: A in 4 row-stripe units/tile (32 rows/half each), B in 2 halves.
// Per iter (compute tiles 2I,2I+1): P1: preread B(2I) + A(2I+1)u2,u3 | P2/P3: B(2I+2) |
// P4: A(2I+2)u0,u1 + vmcnt(6) | P5: preread B(2I+1) + A(2I+2)u2,u3 | P6/P7: B(2I+3) |
// P8: A(2I+3)u0,u1 + vmcnt(6).  Every load >=3 phases of slack before its wait.
template <bool G13, int K, int NBROW>
__global__ __launch_bounds__(512, 2) void k_gemm(
    const unsigned short* __restrict__ A, const unsigned short* __restrict__ B,
    unsigned short* __restrict__ Hout, float* __restrict__ Cout, float* __restrict__ Dout,
    const int* __restrict__ slot_token, const int* __restrict__ offs) {
  __shared__ unsigned short As[2][256 * 64];        // 2 x 32 KiB
  __shared__ unsigned short Bs[2][2][128 * 64];     // 2 x 2 x 16 KiB
  const int NT = K / 64;
  const int NB = G13 ? 16 : 4;                      // bn-blocks per my
  const int TOT = 56 * NB;

  int bid = blockIdx.x;
  int wg = (bid & 7) * (TOT / 8) + (bid >> 3);      // bijective XCD remap (TOT % 8 == 0)
  int my = wg / NB;
  int bn = wg % NB;
  if (my & 1) bn = NB - 1 - bn;                     // serpentine for B-tile L2 reuse

  bool shd = (my >= 40);
  int base = (shd ? my - 40 : my) * 256;
  int e = 8;
  if (!shd) {
    if (base >= offs[8]) return;                    // beyond padded routed total
    e = 0;
    while (e < 7 && base >= offs[e + 1]) ++e;
  }
  int tid = threadIdx.x, lane = tid & 63, w = tid >> 6;

  // staging source byte-offsets (u32), XOR slot swizzle: src slot = (tid&7)^(row&7)
  int srcslot = (((tid & 7) ^ ((tid >> 3) & 7)) << 4);
  unsigned aoff[4];
#pragma unroll
  for (int u = 0; u < 4; u++) {
    int rl = u * 32 + (w & 3) * 8 + ((w >> 2) << 7) + (lane >> 3);
    long row;
    if (G13) row = shd ? (long)(base + rl) : (long)slot_token[base + rl];
    else     row = (long)((shd ? SHSEG : 0) + base + rl);
    aoff[u] = (unsigned)((size_t)row * K * 2) + srcslot;
  }
  unsigned boff[2];
#pragma unroll
  for (int half = 0; half < 2; half++) {
    int br = bn * 256 + half * 128 + (tid >> 3);
    boff[half] = (unsigned)(((size_t)e * NBROW + br) * K * 2) + srcslot;
  }
  const char* Abase = (const char*)A;
  const char* Bbase = (const char*)B;

#define A_STG(b, u, kt) \
  async16(Abase + aoff[u] + (kt) * 128, \
          &As[b][((u) * 32 + (w & 3) * 8 + ((w >> 2) << 7)) * 64])
#define B_STG(b, half, kt) do { \
    async16(Bbase + boff[half] + (size_t)(kt) * 128, &Bs[b][half][(w * 8) * 64]); \
    async16(Bbase + boff[half] + (size_t)64 * K * 2 + (size_t)(kt) * 128, \
            &Bs[b][half][(64 + w * 8) * 64]); \
  } while (0)

  // read-side bases
  int wr = w >> 2, wc = w & 3, wch = wc >> 1;
  const char* LA0 = (const char*)&As[0][0] + (wr * 128 + (lane & 15)) * 128;
  const char* LA1 = (const char*)&As[1][0] + (wr * 128 + (lane & 15)) * 128;
  const char* LB0 = (const char*)&Bs[0][wch][0] + ((wc & 1) * 64 + (lane & 15)) * 128;
  const char* LB1 = (const char*)&Bs[1][wch][0] + ((wc & 1) * 64 + (lane & 15)) * 128;
  int s0 = (((lane >> 4) ^ (lane & 7)) << 4);
  int s1 = (((4 + (lane >> 4)) ^ (lane & 7)) << 4);

  f32x4 acc[8][4];
#pragma unroll
  for (int i = 0; i < 8; i++)
#pragma unroll
    for (int j = 0; j < 4; j++) acc[i][j] = (f32x4){0.f, 0.f, 0.f, 0.f};

  short8 Bf[4][2];

#define PREREAD(LBx) do { \
    _Pragma("unroll") for (int nf = 0; nf < 4; nf++) { \
      Bf[nf][0] = *(const short8*)((LBx) + nf * 2048 + s0); \
      Bf[nf][1] = *(const short8*)((LBx) + nf * 2048 + s1); \
    } \
  } while (0)

#define PHASE(LAx, q, STGS, TAIL) do { \
    short8 Af0k0 = *(const short8*)((LAx) + ((q) * 2 + 0) * 2048 + s0); \
    short8 Af0k1 = *(const short8*)((LAx) + ((q) * 2 + 0) * 2048 + s1); \
    short8 Af1k0 = *(const short8*)((LAx) + ((q) * 2 + 1) * 2048 + s0); \
    short8 Af1k1 = *(const short8*)((LAx) + ((q) * 2 + 1) * 2048 + s1); \
    STGS; \
    BAR(); LGKM0(); SCHED0(); \
    __builtin_amdgcn_s_setprio(1); \
    _Pragma("unroll") for (int nf = 0; nf < 4; nf++) { \
      acc[(q) * 2 + 0][nf] = __builtin_amdgcn_mfma_f32_16x16x32_bf16(Af0k0, Bf[nf][0], acc[(q) * 2 + 0][nf], 0, 0, 0); \
      acc[(q) * 2 + 0][nf] = __builtin_amdgcn_mfma_f32_16x16x32_bf16(Af0k1, Bf[nf][1], acc[(q) * 2 + 0][nf], 0, 0, 0); \
      acc[(q) * 2 + 1][nf] = __builtin_amdgcn_mfma_f32_16x16x32_bf16(Af1k0, Bf[nf][0], acc[(q) * 2 + 1][nf], 0, 0, 0); \
      acc[(q) * 2 + 1][nf] = __builtin_amdgcn_mfma_f32_16x16x32_bf16(Af1k1, Bf[nf][1], acc[(q) * 2 + 1][nf], 0, 0, 0); \
    } \
    __builtin_amdgcn_s_setprio(0); \
    TAIL; \
    BAR(); \
  } while (0)

  // prologue: tile0 (all units) + tile1's B + tile1's A u0,u1 (14 loads); vmcnt(6) drains tile0
  B_STG(0, 0, 0); B_STG(0, 1, 0);
  A_STG(0, 0, 0); A_STG(0, 1, 0); A_STG(0, 2, 0); A_STG(0, 3, 0);
  B_STG(1, 0, 1); B_STG(1, 1, 1);
  A_STG(1, 0, 1); A_STG(1, 1, 1);
  VMWAIT(6);
  BAR();

  const int NIT = NT / 2;
  for (int it = 0; it < NIT; ++it) {
    int kt1 = 2 * it + 1;
    int kt2 = 2 * it + 2; if (kt2 > NT - 1) kt2 = NT - 1;   // tail over-stage: retired regions only
    int kt3 = 2 * it + 3; if (kt3 > NT - 1) kt3 = NT - 1;
    PHASE(LA0, 0, { PREREAD(LB0); A_STG(1, 2, kt1); A_STG(1, 3, kt1); }, {});
    PHASE(LA0, 1, { B_STG(0, 0, kt2); }, {});
    PHASE(LA0, 2, { B_STG(0, 1, kt2); }, {});
    PHASE(LA0, 3, { A_STG(0, 0, kt2); A_STG(0, 1, kt2); }, { VMWAIT(6); });
    PHASE(LA1, 0, { PREREAD(LB1); A_STG(0, 2, kt2); A_STG(0, 3, kt2); }, {});
    PHASE(LA1, 1, { B_STG(1, 0, kt3); }, {});
    PHASE(LA1, 2, { B_STG(1, 1, kt3); }, {});
    PHASE(LA1, 3, { A_STG(1, 0, kt3); A_STG(1, 1, kt3); }, { VMWAIT(6); });
  }
  VMWAIT(0);
#undef PHASE
#undef PREREAD
#undef A_STG
#undef B_STG

  // ---------------- epilogue (no guards: padded slot space) ----------------
  if (G13) {
    size_t hbase = (size_t)(shd ? SHSEG : 0) + base;
#pragma unroll
    for (int mi = 0; mi < 8; mi++)
#pragma unroll
      for (int j = 0; j < 2; j++)
#pragma unroll
        for (int q = 0; q < 4; q++) {
          int rl = wr * 128 + mi * 16 + (lane >> 4) * 4 + q;
          float v1 = acc[mi][2 * j][q], v3 = acc[mi][2 * j + 1][q];
          float h = (v1 / (1.f + __expf(-v1))) * v3;
          int ffcol = (bn * 8 + wc * 2 + j) * 16 + (lane & 15);
          Hout[(hbase + rl) * 2048 + ffcol] = f2bf(h);
        }
  } else {
#pragma unroll
    for (int mi = 0; mi < 8; mi++)
#pragma unroll
      for (int nf = 0; nf < 4; nf++)
#pragma unroll
        for (int q = 0; q < 4; q++) {
          int rl = wr * 128 + mi * 16 + (lane >> 4) * 4 + q;
          int col = bn * 256 + wc * 64 + nf * 16 + (lane & 15);
          if (shd) Dout[(size_t)(base + rl) * 1024 + col] = acc[mi][nf][q];
          else     Cout[(size_t)(base + rl) * 1024 + col] = acc[mi][nf][q];
        }
  }
}

// out[t] = (shared[t] + w0*contrib[s0] + w1*contrib[s1]) / 3   (shared already in out)
__global__ void k_combine(float* __restrict__ out, const float* __restrict__ contrib,
                          const int* __restrict__ token_slot, const float* __restrict__ topkw) {
  int t = blockIdx.x;
  int c = threadIdx.x * 4;
  int s0 = token_slot[t * 2 + 0], s1 = token_slot[t * 2 + 1];
  float w0 = topkw[t * 2 + 0], w1 = topkw[t * 2 + 1];
  float* po = out + (size_t)t * DM + c;
  const float* p0 = contrib + (size_t)s0 * DM + c;
  const float* p1 = contrib + (size_t)s1 * DM + c;
  f32x4 vo = *(f32x4*)po;
  f32x4 v0 = *(const f32x4*)p0;
  f32x4 v1 = *(const f32x4*)p1;
#pragma unroll
  for (int i = 0; i < 4; i++)
    vo[i] = (vo[i] + w0 * v0[i] + w1 * v1[i]) * (1.f / 3.f);
  *(f32x4*)po = vo;
}

// ---------------- launcher ----------------
extern "C" void kernel_launch(void* const* d_in, const int* in_sizes, int n_in,
                              void* d_out, int out_size, void* d_ws, size_t ws_size,
                              hipStream_t stream) {
  const float* x   = (const float*)d_in[0];
  const float* Wg  = (const float*)d_in[1];
  const float* Ws1 = (const float*)d_in[2];
  const float* Ws3 = (const float*)d_in[3];
  const float* Ws2 = (const float*)d_in[4];
  const float* We1 = (const float*)d_in[5];
  const float* We3 = (const float*)d_in[6];
  const float* We2 = (const float*)d_in[7];
  float* out = (float*)d_out;

  if (ws_size < WS_NEEDED) return;

  char* w = (char*)d_ws;
  unsigned short* xb   = (unsigned short*)(w + OFF_XB);
  unsigned short* wb13 = (unsigned short*)(w + OFF_WB13);
  unsigned short* wb2  = (unsigned short*)(w + OFF_WB2);
  unsigned short* H    = (unsigned short*)(w + OFF_H);
  float* contrib       = (float*)(w + OFF_CONTRIB);
  float* topkw         = (float*)(w + OFF_TOPKW);
  int* topki           = (int*)(w + OFF_TOPKI);
  int* slot_token      = (int*)(w + OFF_SLOTTOK);
  int* token_slot      = (int*)(w + OFF_TOKSLOT);
  int* offs            = (int*)(w + OFF_OFFS);

  k_gatecvt<<<TTOK / 4, 256, 0, stream>>>(x, Wg, topkw, topki, xb);
  k_route<<<1, 1024, 0, stream>>>(topki, offs, slot_token, token_slot);
  k_t13<<<dim3(FF / 64, DM / 64, 9), 256, 0, stream>>>(We1, We3, Ws1, Ws3, wb13);
  k_t2<<<dim3(DM / 64, FF / 64, 9), 256, 0, stream>>>(We2, Ws2, wb2);

  k_gemm<true, 1024, 4096><<<896, 512, 0, stream>>>(
      xb, wb13, H, nullptr, nullptr, slot_token, offs);
  k_gemm<false, 2048, 1024><<<224, 512, 0, stream>>>(
      H, wb2, nullptr, contrib, out, slot_token, offs);

  k_combine<<<TTOK, 256, 0, stream>>>(out, contrib, token_slot, topkw);
}

// Round 10
// 319.479 us; speedup vs baseline: 1.0215x; 1.0215x over previous
//
#include <hip/hip_runtime.h>
#include <stdint.h>

#define TTOK 4096
#define DM   1024
#define FF   2048
#define NE   8

typedef __attribute__((ext_vector_type(8))) short short8;
typedef __attribute__((ext_vector_type(8))) unsigned short ushort8;
typedef __attribute__((ext_vector_type(4))) float f32x4;

// ---------------- workspace layout (bytes) ----------------
#define OFF_XB      0ull
#define OFF_WB13    (OFF_XB      + (size_t)TTOK*DM*2)          // [9][4096][1024] bf16 (W1/W3 interleaved 16-row groups)
#define OFF_WB2     (OFF_WB13    + (size_t)9*4096*1024*2)      // [9][1024][2048] bf16
#define OFF_H       (OFF_WB2     + (size_t)9*1024*2048*2)      // [12288][2048] bf16 (slots 0..8191 routed, 8192+ shared)
#define OFF_CONTRIB (OFF_H       + (size_t)12288*2048*2)       // [8192][1024] f32
#define OFF_TOPKW   (OFF_CONTRIB + (size_t)8192*1024*4)
#define OFF_TOPKI   (OFF_TOPKW   + (size_t)TTOK*2*4)
#define OFF_SLOTTOK (OFF_TOPKI   + (size_t)TTOK*2*4)
#define OFF_TOKSLOT (OFF_SLOTTOK + (size_t)TTOK*2*4)
#define OFF_COUNTS  (OFF_TOKSLOT + (size_t)TTOK*2*4)
#define WS_NEEDED   (OFF_COUNTS + 256)

#define VMWAIT(N) asm volatile("s_waitcnt vmcnt(" #N ")" ::: "memory")
#define LGKM0()   asm volatile("s_waitcnt lgkmcnt(0)" ::: "memory")
#define BAR()     __builtin_amdgcn_s_barrier()
#define SCHED0()  __builtin_amdgcn_sched_barrier(0)

__device__ __forceinline__ unsigned short f2bf(float f) {
  unsigned u = __float_as_uint(f);
  return (unsigned short)((u + 0x7FFFu + ((u >> 16) & 1u)) >> 16);
}

__device__ __forceinline__ void async16(const void* g, void* l) {
  __builtin_amdgcn_global_load_lds(
      (const __attribute__((address_space(1))) void*)g,
      (__attribute__((address_space(3))) void*)l, 16, 0, 0);
}

// ---------------- gate (fp32) + x->bf16 convert, vectorized ----------------
__global__ void k_gatecvt(const float* __restrict__ x, const float* __restrict__ Wg,
                          float* __restrict__ topkw, int* __restrict__ topki,
                          unsigned short* __restrict__ xb) {
  int wave = threadIdx.x >> 6;
  int lane = threadIdx.x & 63;
  int t = blockIdx.x * 4 + wave;
  float acc[NE];
#pragma unroll
  for (int e = 0; e < NE; e++) acc[e] = 0.f;
  const float* xr = x + (size_t)t * DM;
  unsigned short* xbr = xb + (size_t)t * DM;
#pragma unroll
  for (int i = 0; i < 4; i++) {
    int k = i * 256 + lane * 4;
    f32x4 xv = *(const f32x4*)(xr + k);
    unsigned short o0 = f2bf(xv[0]), o1 = f2bf(xv[1]), o2 = f2bf(xv[2]), o3 = f2bf(xv[3]);
    unsigned long long pk = (unsigned long long)o0 | ((unsigned long long)o1 << 16) |
                            ((unsigned long long)o2 << 32) | ((unsigned long long)o3 << 48);
    *(unsigned long long*)(xbr + k) = pk;
#pragma unroll
    for (int j = 0; j < 4; j++) {
      const float* wr = Wg + (size_t)(k + j) * NE;
#pragma unroll
      for (int e = 0; e < NE; e++) acc[e] += xv[j] * wr[e];
    }
  }
#pragma unroll
  for (int e = 0; e < NE; e++) {
#pragma unroll
    for (int off = 32; off >= 1; off >>= 1) acc[e] += __shfl_xor(acc[e], off, 64);
  }
  if (lane == 0) {
    float g[NE];
#pragma unroll
    for (int e = 0; e < NE; e++) g[e] = 1.f / (1.f + __expf(-acc[e]));
    int i1 = -1, i2 = -1;
    float m1 = -1e30f, m2 = -1e30f;
#pragma unroll
    for (int e = 0; e < NE; e++) {
      float v = g[e];
      if (v > m1) { m2 = m1; i2 = i1; m1 = v; i1 = e; }
      else if (v > m2) { m2 = v; i2 = e; }
    }
    float s = m1 + m2;
    topkw[t * 2 + 0] = m1 / s;
    topkw[t * 2 + 1] = m2 / s;
    topki[t * 2 + 0] = i1;
    topki[t * 2 + 1] = i2;
  }
}

// single block: count, prefix, scatter
__global__ void k_route(const int* __restrict__ topki, int* __restrict__ counts_g,
                        int* __restrict__ offs_g, int* __restrict__ slot_token,
                        int* __restrict__ token_slot) {
  __shared__ int cnt[NE], off[NE], fill[NE];
  int tid = threadIdx.x;
  if (tid < NE) { cnt[tid] = 0; fill[tid] = 0; }
  __syncthreads();
  for (int t = tid; t < TTOK; t += 1024) {
    atomicAdd(&cnt[topki[t * 2 + 0]], 1);
    atomicAdd(&cnt[topki[t * 2 + 1]], 1);
  }
  __syncthreads();
  if (tid == 0) {
    int s = 0;
    for (int e = 0; e < NE; e++) { off[e] = s; s += cnt[e]; }
  }
  __syncthreads();
  if (tid < NE) { counts_g[tid] = cnt[tid]; offs_g[tid] = off[tid]; }
  for (int t = tid; t < TTOK; t += 1024) {
#pragma unroll
    for (int k = 0; k < 2; k++) {
      int e = topki[t * 2 + k];
      int pos = atomicAdd(&fill[e], 1);
      int slot = off[e] + pos;
      slot_token[slot] = t;
      token_slot[t * 2 + k] = slot;
    }
  }
}

// ---------------- vectorized 64x64 transposes ----------------
// W1/W3 [DM][FF] f32 -> wb13 [z][4096][1024] bf16, W1 col n -> row (n>>4)*32+(n&15), W3 -> +16
__global__ void k_t13(const float* __restrict__ We1, const float* __restrict__ We3,
                      const float* __restrict__ Ws1, const float* __restrict__ Ws3,
                      unsigned short* __restrict__ wb13) {
  __shared__ float tile[64][68];
  int z = blockIdx.z;
  unsigned short* dst = wb13 + (size_t)z * 4096 * 1024;
  int r0 = blockIdx.y * 64;             // k (DM)
  int c0 = blockIdx.x * 64;             // n (FF)
  int tid = threadIdx.x;
  int r = tid >> 2, q = tid & 3;        // load: row r, 4 float4 at cols i*16+q*4
  int nn = tid >> 2, g = tid & 3;       // store: col n=c0+nn, k-group g (16 k's)

  const float* srcs[2] = {(blockIdx.z < 8) ? We1 + (size_t)z * DM * FF : Ws1,
                          (blockIdx.z < 8) ? We3 + (size_t)z * DM * FF : Ws3};
#pragma unroll
  for (int m = 0; m < 2; m++) {
    const float* src = srcs[m] + (size_t)(r0 + r) * FF + c0;
#pragma unroll
    for (int i = 0; i < 4; i++)
      *(f32x4*)&tile[r][i * 16 + q * 4] = *(const f32x4*)(src + i * 16 + q * 4);
    __syncthreads();
    int n = c0 + nn;
    int d = ((n >> 4) << 5) + (n & 15) + m * 16;
    ushort8 o0, o1;
#pragma unroll
    for (int j = 0; j < 8; j++) o0[j] = f2bf(tile[g * 16 + j][nn]);
#pragma unroll
    for (int j = 0; j < 8; j++) o1[j] = f2bf(tile[g * 16 + 8 + j][nn]);
    unsigned short* dp = dst + (size_t)d * 1024 + r0 + g * 16;
    *(ushort8*)dp = o0;
    *(ushort8*)(dp + 8) = o1;
    __syncthreads();
  }
}

// W2 [FF][DM] f32 -> wb2 [z][1024][2048] bf16 (plain transpose)
__global__ void k_t2(const float* __restrict__ We2, const float* __restrict__ Ws2,
                     unsigned short* __restrict__ wb2) {
  __shared__ float tile[64][68];
  int z = blockIdx.z;
  const float* src0 = (z < 8) ? We2 + (size_t)z * FF * DM : Ws2;
  unsigned short* dst = wb2 + (size_t)z * 1024 * 2048;
  int r0 = blockIdx.y * 64;             // k (FF)
  int c0 = blockIdx.x * 64;             // n (DM)
  int tid = threadIdx.x;
  int r = tid >> 2, q = tid & 3;
  int nn = tid >> 2, g = tid & 3;

  const float* src = src0 + (size_t)(r0 + r) * DM + c0;
#pragma unroll
  for (int i = 0; i < 4; i++)
    *(f32x4*)&tile[r][i * 16 + q * 4] = *(const f32x4*)(src + i * 16 + q * 4);
  __syncthreads();
  ushort8 o0, o1;
#pragma unroll
  for (int j = 0; j < 8; j++) o0[j] = f2bf(tile[g * 16 + j][nn]);
#pragma unroll
  for (int j = 0; j < 8; j++) o1[j] = f2bf(tile[g * 16 + 8 + j][nn]);
  unsigned short* dp = dst + (size_t)(c0 + nn) * 2048 + r0 + g * 16;
  *(ushort8*)dp = o0;
  *(ushort8*)(dp + 8) = o1;
}

// ---------------- 256x256 8-phase GEMM, BK=64, 8 waves (2Mx4N), counted vmcnt ----------------
// Schedule per iteration (2 K-tiles: t0=2it->buf0, t1=2it+1->buf1), phases P1..P8:
//   P1..P4 compute t0 (q=0..3), P5..P8 compute t1.  Phase q: mi {2q,2q+1} x 4nf x 2ks = 16 MFMA;
//   q==0 also loads all 8 B-frags (kept in regs for the K-tile) -- B read ONCE per K-tile,
//   which is what makes the stage calendar race-free (B-region writes never collide with reads).
// Stage calendar (1 half-tile/phase, dest retired >=1 barrier earlier):
//   P1: B1h1(t1)  P2: A1h0(t1)  P3: A1h1(t1)  P4: B0h0(t+2) + VMWAIT(2)
//   P5: B0h1(t+2) P6: A0h0(t+2) P7: A0h1(t+2) P8: B1h0(t+3) + VMWAIT(2)
// vmcnt(2) leaves only the newest half-tile in flight => next K-tile's 4 halves have landed.
template <bool G13, int K, int NBROW>
__global__ __launch_bounds__(512, 2) void k_gemm(
    const unsigned short* __restrict__ A, const unsigned short* __restrict__ B,
    unsigned short* __restrict__ Hout, float* __restrict__ Cout, float* __restrict__ Dout,
    const int* __restrict__ slot_token, const int* __restrict__ offs,
    const int* __restrict__ counts) {
  __shared__ unsigned short lds[2][2][2][8192];   // [dbuf][A=0/B=1][half][128*64] = 128 KiB
  const int NT = K / 64;

  int e = blockIdx.z;
  int seg, cnt;
  if (e == 8) { seg = 8192; cnt = 4096; }
  else        { seg = offs[e]; cnt = counts[e]; }
  int m0 = blockIdx.y * 256;
  if (m0 >= cnt) return;
  int bn = blockIdx.x;

  int tid = threadIdx.x, lane = tid & 63, w = tid >> 6;

  // staging source pointers: thread covers rows half*128 + j*64 + (tid>>3), LDS slot tid&7,
  // source slot = (tid&7) ^ (row&7)  (row&7 == (tid>>3)&7 for all half/j)
  int srcslot = (((tid & 7) ^ ((tid >> 3) & 7)) << 4);
  const char* aptr[2][2];
  const char* bptr[2][2];
#pragma unroll
  for (int half = 0; half < 2; half++)
#pragma unroll
    for (int j = 0; j < 2; j++) {
      int rl = half * 128 + j * 64 + (tid >> 3);
      int r = m0 + rl; if (r > cnt - 1) r = cnt - 1;
      long tok;
      if (G13) tok = (e == 8) ? (long)r : (long)slot_token[seg + r];
      else     tok = (long)(seg + r);
      aptr[half][j] = (const char*)A + ((size_t)tok * K) * 2 + srcslot;
      int br = bn * 256 + rl;
      bptr[half][j] = (const char*)B + (((size_t)e * NBROW + br) * K) * 2 + srcslot;
    }

#define STG(b, op, half, kt) do {                                           \
    const char* _p0 = (op ? bptr : aptr)[half][0] + (size_t)(kt) * 128;     \
    const char* _p1 = (op ? bptr : aptr)[half][1] + (size_t)(kt) * 128;     \
    async16(_p0, &lds[b][op][half][(size_t)w * 512]);                       \
    async16(_p1, &lds[b][op][half][4096 + (size_t)w * 512]);                \
  } while (0)

  // read-side: wave (wr, wc); wr in {0,1} -> A-half = wr; wc in {0..3} -> B-half = wc>>1
  int wr = w >> 2, wc = w & 3, wch = wc >> 1;
  int s0 = (((0 + (lane >> 4)) ^ (lane & 7)) << 4);   // ks0 swizzled slot byte-offset
  int s1 = (((4 + (lane >> 4)) ^ (lane & 7)) << 4);   // ks1

  f32x4 acc[8][4];
#pragma unroll
  for (int i = 0; i < 8; i++)
#pragma unroll
    for (int j = 0; j < 4; j++) acc[i][j] = (f32x4){0.f, 0.f, 0.f, 0.f};

  short8 Af[2][2], Bf[4][2];

#define DO_PHASE(LA, LB, qq, STG_STMT, WAIT_STMT) do {                        \
    if (qq == 0) {                                                            \
      _Pragma("unroll") for (int nf = 0; nf < 4; nf++) {                      \
        int rb = ((wc & 1) * 64 + nf * 16 + (lane & 15)) * 128;               \
        Bf[nf][0] = *(const short8*)((LB) + rb + s0);                         \
        Bf[nf][1] = *(const short8*)((LB) + rb + s1);                         \
      }                                                                       \
    }                                                                         \
    _Pragma("unroll") for (int m2 = 0; m2 < 2; m2++) {                        \
      int ra = (((qq) * 2 + m2) * 16 + (lane & 15)) * 128;                    \
      Af[m2][0] = *(const short8*)((LA) + ra + s0);                           \
      Af[m2][1] = *(const short8*)((LA) + ra + s1);                           \
    }                                                                         \
    STG_STMT;                                                                 \
    BAR();                                                                    \
    LGKM0();                                                                  \
    SCHED0();                                                                 \
    __builtin_amdgcn_s_setprio(1);                                            \
    _Pragma("unroll") for (int m2 = 0; m2 < 2; m2++)                          \
      _Pragma("unroll") for (int nf = 0; nf < 4; nf++) {                      \
        acc[(qq) * 2 + m2][nf] = __builtin_amdgcn_mfma_f32_16x16x32_bf16(     \
            Af[m2][0], Bf[nf][0], acc[(qq) * 2 + m2][nf], 0, 0, 0);           \
        acc[(qq) * 2 + m2][nf] = __builtin_amdgcn_mfma_f32_16x16x32_bf16(     \
            Af[m2][1], Bf[nf][1], acc[(qq) * 2 + m2][nf], 0, 0, 0);           \
      }                                                                       \
    __builtin_amdgcn_s_setprio(0);                                            \
    WAIT_STMT;                                                                \
    BAR();                                                                    \
  } while (0)

  // prologue: K-tile0 (4 halves -> buf0) + B1h0 of K-tile1; wait leaves B1h0 in flight
  STG(0, 1, 0, 0);
  STG(0, 1, 1, 0);
  STG(0, 0, 0, 0);
  STG(0, 0, 1, 0);
  STG(1, 1, 0, 1);
  VMWAIT(2);
  BAR();

  const char* LA0 = (const char*)&lds[0][0][wr][0];
  const char* LB0 = (const char*)&lds[0][1][wch][0];
  const char* LA1 = (const char*)&lds[1][0][wr][0];
  const char* LB1 = (const char*)&lds[1][1][wch][0];

  for (int it = 0; it < NT / 2; ++it) {
    int t1 = 2 * it + 1;
    int n2 = (2 * it + 2 < NT) ? 2 * it + 2 : NT - 1;   // clamped over-stage at tail
    int n3 = (2 * it + 3 < NT) ? 2 * it + 3 : NT - 1;   // (lands in retired buffers, never read)
    DO_PHASE(LA0, LB0, 0, STG(1, 1, 1, t1), );              // P1
    DO_PHASE(LA0, LB0, 1, STG(1, 0, 0, t1), );              // P2
    DO_PHASE(LA0, LB0, 2, STG(1, 0, 1, t1), );              // P3
    DO_PHASE(LA0, LB0, 3, STG(0, 1, 0, n2), VMWAIT(2));     // P4
    DO_PHASE(LA1, LB1, 0, STG(0, 1, 1, n2), );              // P5
    DO_PHASE(LA1, LB1, 1, STG(0, 0, 0, n2), );              // P6
    DO_PHASE(LA1, LB1, 2, STG(0, 0, 1, n2), );              // P7
    DO_PHASE(LA1, LB1, 3, STG(1, 1, 0, n3), VMWAIT(2));     // P8
  }
  VMWAIT(0);
#undef DO_PHASE
#undef STG

  // ---------------- epilogue ----------------
  if (G13) {
#pragma unroll
    for (int mi = 0; mi < 8; mi++)
#pragma unroll
      for (int j = 0; j < 2; j++)
#pragma unroll
        for (int q = 0; q < 4; q++) {
          int rl = wr * 128 + mi * 16 + (lane >> 4) * 4 + q;
          if (m0 + rl < cnt) {
            float s1v = acc[mi][2 * j][q], s3v = acc[mi][2 * j + 1][q];
            float h = (s1v / (1.f + __expf(-s1v))) * s3v;
            int ffcol = (bn * 8 + wc * 2 + j) * 16 + (lane & 15);
            Hout[(size_t)(seg + m0 + rl) * 2048 + ffcol] = f2bf(h);
          }
        }
  } else {
#pragma unroll
    for (int mi = 0; mi < 8; mi++)
#pragma unroll
      for (int nf = 0; nf < 4; nf++)
#pragma unroll
        for (int q = 0; q < 4; q++) {
          int rl = wr * 128 + mi * 16 + (lane >> 4) * 4 + q;
          if (m0 + rl < cnt) {
            int col = bn * 256 + wc * 64 + nf * 16 + (lane & 15);
            if (e == 8) Dout[(size_t)(m0 + rl) * 1024 + col] = acc[mi][nf][q];
            else        Cout[(size_t)(seg + m0 + rl) * 1024 + col] = acc[mi][nf][q];
          }
        }
  }
}

// out[t] = (shared[t] + w0*contrib[s0] + w1*contrib[s1]) / 3   (shared already in out)
__global__ void k_combine(float* __restrict__ out, const float* __restrict__ contrib,
                          const int* __restrict__ token_slot, const float* __restrict__ topkw) {
  int t = blockIdx.x;
  int c = threadIdx.x * 4;
  int s0 = token_slot[t * 2 + 0], s1 = token_slot[t * 2 + 1];
  float w0 = topkw[t * 2 + 0], w1 = topkw[t * 2 + 1];
  float* po = out + (size_t)t * DM + c;
  const float* p0 = contrib + (size_t)s0 * DM + c;
  const float* p1 = contrib + (size_t)s1 * DM + c;
  f32x4 vo = *(f32x4*)po;
  f32x4 v0 = *(const f32x4*)p0;
  f32x4 v1 = *(const f32x4*)p1;
#pragma unroll
  for (int i = 0; i < 4; i++)
    vo[i] = (vo[i] + w0 * v0[i] + w1 * v1[i]) * (1.f / 3.f);
  *(f32x4*)po = vo;
}

// ---------------- launcher ----------------
extern "C" void kernel_launch(void* const* d_in, const int* in_sizes, int n_in,
                              void* d_out, int out_size, void* d_ws, size_t ws_size,
                              hipStream_t stream) {
  const float* x   = (const float*)d_in[0];
  const float* Wg  = (const float*)d_in[1];
  const float* Ws1 = (const float*)d_in[2];
  const float* Ws3 = (const float*)d_in[3];
  const float* Ws2 = (const float*)d_in[4];
  const float* We1 = (const float*)d_in[5];
  const float* We3 = (const float*)d_in[6];
  const float* We2 = (const float*)d_in[7];
  float* out = (float*)d_out;

  if (ws_size < WS_NEEDED) return;

  char* w = (char*)d_ws;
  unsigned short* xb   = (unsigned short*)(w + OFF_XB);
  unsigned short* wb13 = (unsigned short*)(w + OFF_WB13);
  unsigned short* wb2  = (unsigned short*)(w + OFF_WB2);
  unsigned short* H    = (unsigned short*)(w + OFF_H);
  float* contrib       = (float*)(w + OFF_CONTRIB);
  float* topkw         = (float*)(w + OFF_TOPKW);
  int* topki           = (int*)(w + OFF_TOPKI);
  int* slot_token      = (int*)(w + OFF_SLOTTOK);
  int* token_slot      = (int*)(w + OFF_TOKSLOT);
  int* counts          = (int*)(w + OFF_COUNTS);
  int* offs            = counts + 16;

  k_gatecvt<<<TTOK / 4, 256, 0, stream>>>(x, Wg, topkw, topki, xb);
  k_route<<<1, 1024, 0, stream>>>(topki, counts, offs, slot_token, token_slot);
  k_t13<<<dim3(FF / 64, DM / 64, 9), 256, 0, stream>>>(We1, We3, Ws1, Ws3, wb13);
  k_t2<<<dim3(DM / 64, FF / 64, 9), 256, 0, stream>>>(We2, Ws2, wb2);

  k_gemm<true, 1024, 4096><<<dim3(16, 16, 9), 512, 0, stream>>>(
      xb, wb13, H, nullptr, nullptr, slot_token, offs, counts);
  k_gemm<false, 2048, 1024><<<dim3(4, 16, 9), 512, 0, stream>>>(
      H, wb2, nullptr, contrib, out, slot_token, offs, counts);

  k_combine<<<TTOK, 256, 0, stream>>>(out, contrib, token_slot, topkw);
}

// Round 12
// 319.010 us; speedup vs baseline: 1.0230x; 1.0015x over previous
//
#include <hip/hip_runtime.h>
#include <stdint.h>

#define TTOK 4096
#define DM   1024
#define FF   2048
#define NE   8

typedef __attribute__((ext_vector_type(8))) short short8;
typedef __attribute__((ext_vector_type(8))) unsigned short ushort8;
typedef __attribute__((ext_vector_type(4))) unsigned short u16x4;
typedef __attribute__((ext_vector_type(4))) float f32x4;

// ---------------- workspace layout (bytes) ----------------
#define OFF_XB      0ull
#define OFF_WB13    (OFF_XB      + (size_t)TTOK*DM*2)          // [9][4096][1024] bf16 (W1/W3 interleaved 16-row groups)
#define OFF_WB2     (OFF_WB13    + (size_t)9*4096*1024*2)      // [9][1024][2048] bf16
#define OFF_H       (OFF_WB2     + (size_t)9*1024*2048*2)      // [12288][2048] bf16 (slots 0..8191 routed, 8192+ shared)
#define OFF_CONTRIB (OFF_H       + (size_t)12288*2048*2)       // [8192][1024] bf16 (region sized for f32; bf16 used)
#define OFF_TOPKW   (OFF_CONTRIB + (size_t)8192*1024*4)
#define OFF_TOPKI   (OFF_TOPKW   + (size_t)TTOK*2*4)
#define OFF_SLOTTOK (OFF_TOPKI   + (size_t)TTOK*2*4)
#define OFF_TOKSLOT (OFF_SLOTTOK + (size_t)TTOK*2*4)
#define OFF_COUNTS  (OFF_TOKSLOT + (size_t)TTOK*2*4)
#define WS_NEEDED   (OFF_COUNTS + 256)

#define VMWAIT(N) asm volatile("s_waitcnt vmcnt(" #N ")" ::: "memory")
#define LGKM0()   asm volatile("s_waitcnt lgkmcnt(0)" ::: "memory")
#define BAR()     __builtin_amdgcn_s_barrier()
#define SCHED0()  __builtin_amdgcn_sched_barrier(0)

__device__ __forceinline__ unsigned short f2bf(float f) {
  unsigned u = __float_as_uint(f);
  return (unsigned short)((u + 0x7FFFu + ((u >> 16) & 1u)) >> 16);
}
__device__ __forceinline__ float bf2f(unsigned short b) {
  return __uint_as_float((unsigned)b << 16);
}

__device__ __forceinline__ void async16(const void* g, void* l) {
  __builtin_amdgcn_global_load_lds(
      (const __attribute__((address_space(1))) void*)g,
      (__attribute__((address_space(3))) void*)l, 16, 0, 0);
}

// ---------------- gate (fp32) + x->bf16 convert, vectorized ----------------
__global__ void k_gatecvt(const float* __restrict__ x, const float* __restrict__ Wg,
                          float* __restrict__ topkw, int* __restrict__ topki,
                          unsigned short* __restrict__ xb) {
  int wave = threadIdx.x >> 6;
  int lane = threadIdx.x & 63;
  int t = blockIdx.x * 4 + wave;
  float acc[NE];
#pragma unroll
  for (int e = 0; e < NE; e++) acc[e] = 0.f;
  const float* xr = x + (size_t)t * DM;
  unsigned short* xbr = xb + (size_t)t * DM;
#pragma unroll
  for (int i = 0; i < 4; i++) {
    int k = i * 256 + lane * 4;
    f32x4 xv = *(const f32x4*)(xr + k);
    unsigned short o0 = f2bf(xv[0]), o1 = f2bf(xv[1]), o2 = f2bf(xv[2]), o3 = f2bf(xv[3]);
    unsigned long long pk = (unsigned long long)o0 | ((unsigned long long)o1 << 16) |
                            ((unsigned long long)o2 << 32) | ((unsigned long long)o3 << 48);
    *(unsigned long long*)(xbr + k) = pk;
#pragma unroll
    for (int j = 0; j < 4; j++) {
      const float* wr = Wg + (size_t)(k + j) * NE;
#pragma unroll
      for (int e = 0; e < NE; e++) acc[e] += xv[j] * wr[e];
    }
  }
#pragma unroll
  for (int e = 0; e < NE; e++) {
#pragma unroll
    for (int off = 32; off >= 1; off >>= 1) acc[e] += __shfl_xor(acc[e], off, 64);
  }
  if (lane == 0) {
    float g[NE];
#pragma unroll
    for (int e = 0; e < NE; e++) g[e] = 1.f / (1.f + __expf(-acc[e]));
    int i1 = -1, i2 = -1;
    float m1 = -1e30f, m2 = -1e30f;
#pragma unroll
    for (int e = 0; e < NE; e++) {
      float v = g[e];
      if (v > m1) { m2 = m1; i2 = i1; m1 = v; i1 = e; }
      else if (v > m2) { m2 = v; i2 = e; }
    }
    float s = m1 + m2;
    topkw[t * 2 + 0] = m1 / s;
    topkw[t * 2 + 1] = m2 / s;
    topki[t * 2 + 0] = i1;
    topki[t * 2 + 1] = i2;
  }
}

// single block: count, prefix, scatter
__global__ void k_route(const int* __restrict__ topki, int* __restrict__ counts_g,
                        int* __restrict__ offs_g, int* __restrict__ slot_token,
                        int* __restrict__ token_slot) {
  __shared__ int cnt[NE], off[NE], fill[NE];
  int tid = threadIdx.x;
  if (tid < NE) { cnt[tid] = 0; fill[tid] = 0; }
  __syncthreads();
  for (int t = tid; t < TTOK; t += 1024) {
    atomicAdd(&cnt[topki[t * 2 + 0]], 1);
    atomicAdd(&cnt[topki[t * 2 + 1]], 1);
  }
  __syncthreads();
  if (tid == 0) {
    int s = 0;
    for (int e = 0; e < NE; e++) { off[e] = s; s += cnt[e]; }
  }
  __syncthreads();
  if (tid < NE) { counts_g[tid] = cnt[tid]; offs_g[tid] = off[tid]; }
  for (int t = tid; t < TTOK; t += 1024) {
#pragma unroll
    for (int k = 0; k < 2; k++) {
      int e = topki[t * 2 + k];
      int pos = atomicAdd(&fill[e], 1);
      int slot = off[e] + pos;
      slot_token[slot] = t;
      token_slot[t * 2 + k] = slot;
    }
  }
}

// ---------------- merged vectorized 64x64 weight transposes (t13 + t2 in one launch) ----
// blocks 0..4607:    W1/W3 [DM][FF] f32 -> wb13 [z][4096][1024] bf16 (W1 col n -> row
//                    (n>>4)*32+(n&15), W3 -> +16); per z: 512 blocks = 16 y x 32 x
// blocks 4608..9215: W2 [FF][DM] f32 -> wb2 [z][1024][2048] bf16;  per z: 512 = 32 y x 16 x
__global__ void k_tw(const float* __restrict__ We1, const float* __restrict__ We3,
                     const float* __restrict__ Ws1, const float* __restrict__ Ws3,
                     const float* __restrict__ We2, const float* __restrict__ Ws2,
                     unsigned short* __restrict__ wb13, unsigned short* __restrict__ wb2) {
  __shared__ float tile[64][68];
  int bid = blockIdx.x;
  int tid = threadIdx.x;
  int r = tid >> 2, q = tid & 3;        // load: row r, float4 at cols i*16+q*4
  int nn = tid >> 2, g = tid & 3;       // store: col nn, k-group g

  if (bid < 4608) {
    int z = bid >> 9, rem = bid & 511;
    int by = rem >> 5, bx = rem & 31;
    int r0 = by * 64, c0 = bx * 64;     // r0: k (DM), c0: n (FF)
    unsigned short* dst = wb13 + (size_t)z * 4096 * 1024;
    const float* srcs[2] = {(z < 8) ? We1 + (size_t)z * DM * FF : Ws1,
                            (z < 8) ? We3 + (size_t)z * DM * FF : Ws3};
#pragma unroll
    for (int m = 0; m < 2; m++) {
      const float* src = srcs[m] + (size_t)(r0 + r) * FF + c0;
#pragma unroll
      for (int i = 0; i < 4; i++)
        *(f32x4*)&tile[r][i * 16 + q * 4] = *(const f32x4*)(src + i * 16 + q * 4);
      __syncthreads();
      int n = c0 + nn;
      int d = ((n >> 4) << 5) + (n & 15) + m * 16;
      ushort8 o0, o1;
#pragma unroll
      for (int j = 0; j < 8; j++) o0[j] = f2bf(tile[g * 16 + j][nn]);
#pragma unroll
      for (int j = 0; j < 8; j++) o1[j] = f2bf(tile[g * 16 + 8 + j][nn]);
      unsigned short* dp = dst + (size_t)d * 1024 + r0 + g * 16;
      *(ushort8*)dp = o0;
      *(ushort8*)(dp + 8) = o1;
      __syncthreads();
    }
  } else {
    bid -= 4608;
    int z = bid >> 9, rem = bid & 511;
    int by = rem >> 4, bx = rem & 15;
    int r0 = by * 64, c0 = bx * 64;     // r0: k (FF), c0: n (DM)
    const float* src0 = (z < 8) ? We2 + (size_t)z * FF * DM : Ws2;
    unsigned short* dst = wb2 + (size_t)z * 1024 * 2048;
    const float* src = src0 + (size_t)(r0 + r) * DM + c0;
#pragma unroll
    for (int i = 0; i < 4; i++)
      *(f32x4*)&tile[r][i * 16 + q * 4] = *(const f32x4*)(src + i * 16 + q * 4);
    __syncthreads();
    ushort8 o0, o1;
#pragma unroll
    for (int j = 0; j < 8; j++) o0[j] = f2bf(tile[g * 16 + j][nn]);
#pragma unroll
    for (int j = 0; j < 8; j++) o1[j] = f2bf(tile[g * 16 + 8 + j][nn]);
    unsigned short* dp = dst + (size_t)(c0 + nn) * 2048 + r0 + g * 16;
    *(ushort8*)dp = o0;
    *(ushort8*)(dp + 8) = o1;
  }
}

// ---------------- 256x256 8-phase GEMM, BK=64, 8 waves (2Mx4N), counted vmcnt ----------------
// (R5/R10 verbatim schedule — verified race-free; B read once per K-tile at q0.)
//   P1: B1h1(t1)  P2: A1h0(t1)  P3: A1h1(t1)  P4: B0h0(t+2) + VMWAIT(2)
//   P5: B0h1(t+2) P6: A0h0(t+2) P7: A0h1(t+2) P8: B1h0(t+3) + VMWAIT(2)
template <bool G13, int K, int NBROW>
__global__ __launch_bounds__(512, 2) void k_gemm(
    const unsigned short* __restrict__ A, const unsigned short* __restrict__ B,
    unsigned short* __restrict__ Hout, unsigned short* __restrict__ Cout,
    float* __restrict__ Dout,
    const int* __restrict__ slot_token, const int* __restrict__ offs,
    const int* __restrict__ counts) {
  __shared__ unsigned short lds[2][2][2][8192];   // [dbuf][A=0/B=1][half][128*64] = 128 KiB
  const int NT = K / 64;

  int e = blockIdx.z;
  int seg, cnt;
  if (e == 8) { seg = 8192; cnt = 4096; }
  else        { seg = offs[e]; cnt = counts[e]; }
  int m0 = blockIdx.y * 256;
  if (m0 >= cnt) return;
  int bn = blockIdx.x;

  int tid = threadIdx.x, lane = tid & 63, w = tid >> 6;

  int srcslot = (((tid & 7) ^ ((tid >> 3) & 7)) << 4);
  const char* aptr[2][2];
  const char* bptr[2][2];
#pragma unroll
  for (int half = 0; half < 2; half++)
#pragma unroll
    for (int j = 0; j < 2; j++) {
      int rl = half * 128 + j * 64 + (tid >> 3);
      int r = m0 + rl; if (r > cnt - 1) r = cnt - 1;
      long tok;
      if (G13) tok = (e == 8) ? (long)r : (long)slot_token[seg + r];
      else     tok = (long)(seg + r);
      aptr[half][j] = (const char*)A + ((size_t)tok * K) * 2 + srcslot;
      int br = bn * 256 + rl;
      bptr[half][j] = (const char*)B + (((size_t)e * NBROW + br) * K) * 2 + srcslot;
    }

#define STG(b, op, half, kt) do {                                           \
    const char* _p0 = (op ? bptr : aptr)[half][0] + (size_t)(kt) * 128;     \
    const char* _p1 = (op ? bptr : aptr)[half][1] + (size_t)(kt) * 128;     \
    async16(_p0, &lds[b][op][half][(size_t)w * 512]);                       \
    async16(_p1, &lds[b][op][half][4096 + (size_t)w * 512]);                \
  } while (0)

  int wr = w >> 2, wc = w & 3, wch = wc >> 1;
  int s0 = (((0 + (lane >> 4)) ^ (lane & 7)) << 4);
  int s1 = (((4 + (lane >> 4)) ^ (lane & 7)) << 4);

  f32x4 acc[8][4];
#pragma unroll
  for (int i = 0; i < 8; i++)
#pragma unroll
    for (int j = 0; j < 4; j++) acc[i][j] = (f32x4){0.f, 0.f, 0.f, 0.f};

  short8 Af[2][2], Bf[4][2];

#define DO_PHASE(LA, LB, qq, STG_STMT, WAIT_STMT) do {                        \
    if (qq == 0) {                                                            \
      _Pragma("unroll") for (int nf = 0; nf < 4; nf++) {                      \
        int rb = ((wc & 1) * 64 + nf * 16 + (lane & 15)) * 128;               \
        Bf[nf][0] = *(const short8*)((LB) + rb + s0);                         \
        Bf[nf][1] = *(const short8*)((LB) + rb + s1);                         \
      }                                                                       \
    }                                                                         \
    _Pragma("unroll") for (int m2 = 0; m2 < 2; m2++) {                        \
      int ra = (((qq) * 2 + m2) * 16 + (lane & 15)) * 128;                    \
      Af[m2][0] = *(const short8*)((LA) + ra + s0);                           \
      Af[m2][1] = *(const short8*)((LA) + ra + s1);                           \
    }                                                                         \
    STG_STMT;                                                                 \
    BAR();                                                                    \
    LGKM0();                                                                  \
    SCHED0();                                                                 \
    __builtin_amdgcn_s_setprio(1);                                            \
    _Pragma("unroll") for (int m2 = 0; m2 < 2; m2++)                          \
      _Pragma("unroll") for (int nf = 0; nf < 4; nf++) {                      \
        acc[(qq) * 2 + m2][nf] = __builtin_amdgcn_mfma_f32_16x16x32_bf16(     \
            Af[m2][0], Bf[nf][0], acc[(qq) * 2 + m2][nf], 0, 0, 0);           \
        acc[(qq) * 2 + m2][nf] = __builtin_amdgcn_mfma_f32_16x16x32_bf16(     \
            Af[m2][1], Bf[nf][1], acc[(qq) * 2 + m2][nf], 0, 0, 0);           \
      }                                                                       \
    __builtin_amdgcn_s_setprio(0);                                            \
    WAIT_STMT;                                                                \
    BAR();                                                                    \
  } while (0)

  STG(0, 1, 0, 0);
  STG(0, 1, 1, 0);
  STG(0, 0, 0, 0);
  STG(0, 0, 1, 0);
  STG(1, 1, 0, 1);
  VMWAIT(2);
  BAR();

  const char* LA0 = (const char*)&lds[0][0][wr][0];
  const char* LB0 = (const char*)&lds[0][1][wch][0];
  const char* LA1 = (const char*)&lds[1][0][wr][0];
  const char* LB1 = (const char*)&lds[1][1][wch][0];

  for (int it = 0; it < NT / 2; ++it) {
    int t1 = 2 * it + 1;
    int n2 = (2 * it + 2 < NT) ? 2 * it + 2 : NT - 1;   // clamped over-stage at tail
    int n3 = (2 * it + 3 < NT) ? 2 * it + 3 : NT - 1;   // (lands in retired buffers, never read)
    DO_PHASE(LA0, LB0, 0, STG(1, 1, 1, t1), );              // P1
    DO_PHASE(LA0, LB0, 1, STG(1, 0, 0, t1), );              // P2
    DO_PHASE(LA0, LB0, 2, STG(1, 0, 1, t1), );              // P3
    DO_PHASE(LA0, LB0, 3, STG(0, 1, 0, n2), VMWAIT(2));     // P4
    DO_PHASE(LA1, LB1, 0, STG(0, 1, 1, n2), );              // P5
    DO_PHASE(LA1, LB1, 1, STG(0, 0, 0, n2), );              // P6
    DO_PHASE(LA1, LB1, 2, STG(0, 0, 1, n2), );              // P7
    DO_PHASE(LA1, LB1, 3, STG(1, 1, 0, n3), VMWAIT(2));     // P8
  }
  VMWAIT(0);
#undef DO_PHASE
#undef STG

  // ---------------- epilogue ----------------
  if (G13) {
#pragma unroll
    for (int mi = 0; mi < 8; mi++)
#pragma unroll
      for (int j = 0; j < 2; j++)
#pragma unroll
        for (int q = 0; q < 4; q++) {
          int rl = wr * 128 + mi * 16 + (lane >> 4) * 4 + q;
          if (m0 + rl < cnt) {
            float s1v = acc[mi][2 * j][q], s3v = acc[mi][2 * j + 1][q];
            float h = (s1v / (1.f + __expf(-s1v))) * s3v;
            int ffcol = (bn * 8 + wc * 2 + j) * 16 + (lane & 15);
            Hout[(size_t)(seg + m0 + rl) * 2048 + ffcol] = f2bf(h);
          }
        }
  } else {
#pragma unroll
    for (int mi = 0; mi < 8; mi++)
#pragma unroll
      for (int nf = 0; nf < 4; nf++)
#pragma unroll
        for (int q = 0; q < 4; q++) {
          int rl = wr * 128 + mi * 16 + (lane >> 4) * 4 + q;
          if (m0 + rl < cnt) {
            int col = bn * 256 + wc * 64 + nf * 16 + (lane & 15);
            if (e == 8) Dout[(size_t)(m0 + rl) * 1024 + col] = acc[mi][nf][q];
            else        Cout[(size_t)(seg + m0 + rl) * 1024 + col] = f2bf(acc[mi][nf][q]);
          }
        }
  }
}

// out[t] = (shared[t] + w0*contrib[s0] + w1*contrib[s1]) / 3   (shared already in out; contrib bf16)
__global__ void k_combine(float* __restrict__ out, const unsigned short* __restrict__ contrib,
                          const int* __restrict__ token_slot, const float* __restrict__ topkw) {
  int t = blockIdx.x;
  int c = threadIdx.x * 4;
  int s0 = token_slot[t * 2 + 0], s1 = token_slot[t * 2 + 1];
  float w0 = topkw[t * 2 + 0], w1 = topkw[t * 2 + 1];
  float* po = out + (size_t)t * DM + c;
  const unsigned short* p0 = contrib + (size_t)s0 * DM + c;
  const unsigned short* p1 = contrib + (size_t)s1 * DM + c;
  f32x4 vo = *(f32x4*)po;
  u16x4 v0 = *(const u16x4*)p0;
  u16x4 v1 = *(const u16x4*)p1;
#pragma unroll
  for (int i = 0; i < 4; i++)
    vo[i] = (vo[i] + w0 * bf2f(v0[i]) + w1 * bf2f(v1[i])) * (1.f / 3.f);
  *(f32x4*)po = vo;
}

// ---------------- launcher ----------------
extern "C" void kernel_launch(void* const* d_in, const int* in_sizes, int n_in,
                              void* d_out, int out_size, void* d_ws, size_t ws_size,
                              hipStream_t stream) {
  const float* x   = (const float*)d_in[0];
  const float* Wg  = (const float*)d_in[1];
  const float* Ws1 = (const float*)d_in[2];
  const float* Ws3 = (const float*)d_in[3];
  const float* Ws2 = (const float*)d_in[4];
  const float* We1 = (const float*)d_in[5];
  const float* We3 = (const float*)d_in[6];
  const float* We2 = (const float*)d_in[7];
  float* out = (float*)d_out;

  if (ws_size < WS_NEEDED) return;

  char* w = (char*)d_ws;
  unsigned short* xb      = (unsigned short*)(w + OFF_XB);
  unsigned short* wb13    = (unsigned short*)(w + OFF_WB13);
  unsigned short* wb2     = (unsigned short*)(w + OFF_WB2);
  unsigned short* H       = (unsigned short*)(w + OFF_H);
  unsigned short* contrib = (unsigned short*)(w + OFF_CONTRIB);
  float* topkw            = (float*)(w + OFF_TOPKW);
  int* topki              = (int*)(w + OFF_TOPKI);
  int* slot_token         = (int*)(w + OFF_SLOTTOK);
  int* token_slot         = (int*)(w + OFF_TOKSLOT);
  int* counts             = (int*)(w + OFF_COUNTS);
  int* offs               = counts + 16;

  k_gatecvt<<<TTOK / 4, 256, 0, stream>>>(x, Wg, topkw, topki, xb);
  k_route<<<1, 1024, 0, stream>>>(topki, counts, offs, slot_token, token_slot);
  k_tw<<<9216, 256, 0, stream>>>(We1, We3, Ws1, Ws3, We2, Ws2, wb13, wb2);

  k_gemm<true, 1024, 4096><<<dim3(16, 16, 9), 512, 0, stream>>>(
      xb, wb13, H, nullptr, nullptr, slot_token, offs, counts);
  k_gemm<false, 2048, 1024><<<dim3(4, 16, 9), 512, 0, stream>>>(
      H, wb2, nullptr, contrib, out, slot_token, offs, counts);

  k_combine<<<TTOK, 256, 0, stream>>>(out, contrib, token_slot, topkw);
}

// Round 13
// 316.080 us; speedup vs baseline: 1.0325x; 1.0093x over previous
//
#include <hip/hip_runtime.h>
#include <stdint.h>

#define TTOK 4096
#define DM   1024
#define FF   2048
#define NE   8

typedef __attribute__((ext_vector_type(8))) short short8;
typedef __attribute__((ext_vector_type(8))) unsigned short ushort8;
typedef __attribute__((ext_vector_type(4))) unsigned short u16x4;
typedef __attribute__((ext_vector_type(4))) float f32x4;

// ---------------- workspace layout (bytes) ----------------
#define OFF_XB      0ull
#define OFF_WB13    (OFF_XB      + (size_t)TTOK*DM*2)          // [9][4096][1024] bf16; after g13: partials 0..2 (3 x 12288 x 1024 bf16 = exactly this size)
#define OFF_WB2     (OFF_WB13    + (size_t)9*4096*1024*2)      // [9][1024][2048] bf16
#define OFF_H       (OFF_WB2     + (size_t)9*1024*2048*2)      // [12288][2048] bf16 (slots 0..8191 routed, 8192+ shared)
#define OFF_CONTRIB (OFF_H       + (size_t)12288*2048*2)       // partial 3: [12288][1024] bf16 (region sized 8192*1024*4)
#define OFF_TOPKW   (OFF_CONTRIB + (size_t)8192*1024*4)
#define OFF_TOPKI   (OFF_TOPKW   + (size_t)TTOK*2*4)
#define OFF_SLOTTOK (OFF_TOPKI   + (size_t)TTOK*2*4)
#define OFF_TOKSLOT (OFF_SLOTTOK + (size_t)TTOK*2*4)
#define OFF_COUNTS  (OFF_TOKSLOT + (size_t)TTOK*2*4)
#define WS_NEEDED   (OFF_COUNTS + 256)

#define PARTROWS    ((size_t)12288 * 1024)                     // u16 elements per partial

#define VMWAIT(N) asm volatile("s_waitcnt vmcnt(" #N ")" ::: "memory")
#define LGKM0()   asm volatile("s_waitcnt lgkmcnt(0)" ::: "memory")
#define BAR()     __builtin_amdgcn_s_barrier()
#define SCHED0()  __builtin_amdgcn_sched_barrier(0)

__device__ __forceinline__ unsigned short f2bf(float f) {
  unsigned u = __float_as_uint(f);
  return (unsigned short)((u + 0x7FFFu + ((u >> 16) & 1u)) >> 16);
}
__device__ __forceinline__ float bf2f(unsigned short b) {
  return __uint_as_float((unsigned)b << 16);
}

__device__ __forceinline__ void async16(const void* g, void* l) {
  __builtin_amdgcn_global_load_lds(
      (const __attribute__((address_space(1))) void*)g,
      (__attribute__((address_space(3))) void*)l, 16, 0, 0);
}

// ---------------- gate (fp32) + x->bf16 convert, vectorized ----------------
__global__ void k_gatecvt(const float* __restrict__ x, const float* __restrict__ Wg,
                          float* __restrict__ topkw, int* __restrict__ topki,
                          unsigned short* __restrict__ xb) {
  int wave = threadIdx.x >> 6;
  int lane = threadIdx.x & 63;
  int t = blockIdx.x * 4 + wave;
  float acc[NE];
#pragma unroll
  for (int e = 0; e < NE; e++) acc[e] = 0.f;
  const float* xr = x + (size_t)t * DM;
  unsigned short* xbr = xb + (size_t)t * DM;
#pragma unroll
  for (int i = 0; i < 4; i++) {
    int k = i * 256 + lane * 4;
    f32x4 xv = *(const f32x4*)(xr + k);
    unsigned short o0 = f2bf(xv[0]), o1 = f2bf(xv[1]), o2 = f2bf(xv[2]), o3 = f2bf(xv[3]);
    unsigned long long pk = (unsigned long long)o0 | ((unsigned long long)o1 << 16) |
                            ((unsigned long long)o2 << 32) | ((unsigned long long)o3 << 48);
    *(unsigned long long*)(xbr + k) = pk;
#pragma unroll
    for (int j = 0; j < 4; j++) {
      const float* wr = Wg + (size_t)(k + j) * NE;
#pragma unroll
      for (int e = 0; e < NE; e++) acc[e] += xv[j] * wr[e];
    }
  }
#pragma unroll
  for (int e = 0; e < NE; e++) {
#pragma unroll
    for (int off = 32; off >= 1; off >>= 1) acc[e] += __shfl_xor(acc[e], off, 64);
  }
  if (lane == 0) {
    float g[NE];
#pragma unroll
    for (int e = 0; e < NE; e++) g[e] = 1.f / (1.f + __expf(-acc[e]));
    int i1 = -1, i2 = -1;
    float m1 = -1e30f, m2 = -1e30f;
#pragma unroll
    for (int e = 0; e < NE; e++) {
      float v = g[e];
      if (v > m1) { m2 = m1; i2 = i1; m1 = v; i1 = e; }
      else if (v > m2) { m2 = v; i2 = e; }
    }
    float s = m1 + m2;
    topkw[t * 2 + 0] = m1 / s;
    topkw[t * 2 + 1] = m2 / s;
    topki[t * 2 + 0] = i1;
    topki[t * 2 + 1] = i2;
  }
}

// single block: count, prefix, scatter
__global__ void k_route(const int* __restrict__ topki, int* __restrict__ counts_g,
                        int* __restrict__ offs_g, int* __restrict__ slot_token,
                        int* __restrict__ token_slot) {
  __shared__ int cnt[NE], off[NE], fill[NE];
  int tid = threadIdx.x;
  if (tid < NE) { cnt[tid] = 0; fill[tid] = 0; }
  __syncthreads();
  for (int t = tid; t < TTOK; t += 1024) {
    atomicAdd(&cnt[topki[t * 2 + 0]], 1);
    atomicAdd(&cnt[topki[t * 2 + 1]], 1);
  }
  __syncthreads();
  if (tid == 0) {
    int s = 0;
    for (int e = 0; e < NE; e++) { off[e] = s; s += cnt[e]; }
  }
  __syncthreads();
  if (tid < NE) { counts_g[tid] = cnt[tid]; offs_g[tid] = off[tid]; }
  for (int t = tid; t < TTOK; t += 1024) {
#pragma unroll
    for (int k = 0; k < 2; k++) {
      int e = topki[t * 2 + k];
      int pos = atomicAdd(&fill[e], 1);
      int slot = off[e] + pos;
      slot_token[slot] = t;
      token_slot[t * 2 + k] = slot;
    }
  }
}

// ---------------- merged vectorized 64x64 weight transposes (t13 + t2 in one launch) ----
__global__ void k_tw(const float* __restrict__ We1, const float* __restrict__ We3,
                     const float* __restrict__ Ws1, const float* __restrict__ Ws3,
                     const float* __restrict__ We2, const float* __restrict__ Ws2,
                     unsigned short* __restrict__ wb13, unsigned short* __restrict__ wb2) {
  __shared__ float tile[64][68];
  int bid = blockIdx.x;
  int tid = threadIdx.x;
  int r = tid >> 2, q = tid & 3;
  int nn = tid >> 2, g = tid & 3;

  if (bid < 4608) {
    int z = bid >> 9, rem = bid & 511;
    int by = rem >> 5, bx = rem & 31;
    int r0 = by * 64, c0 = bx * 64;     // r0: k (DM), c0: n (FF)
    unsigned short* dst = wb13 + (size_t)z * 4096 * 1024;
    const float* srcs[2] = {(z < 8) ? We1 + (size_t)z * DM * FF : Ws1,
                            (z < 8) ? We3 + (size_t)z * DM * FF : Ws3};
#pragma unroll
    for (int m = 0; m < 2; m++) {
      const float* src = srcs[m] + (size_t)(r0 + r) * FF + c0;
#pragma unroll
      for (int i = 0; i < 4; i++)
        *(f32x4*)&tile[r][i * 16 + q * 4] = *(const f32x4*)(src + i * 16 + q * 4);
      __syncthreads();
      int n = c0 + nn;
      int d = ((n >> 4) << 5) + (n & 15) + m * 16;
      ushort8 o0, o1;
#pragma unroll
      for (int j = 0; j < 8; j++) o0[j] = f2bf(tile[g * 16 + j][nn]);
#pragma unroll
      for (int j = 0; j < 8; j++) o1[j] = f2bf(tile[g * 16 + 8 + j][nn]);
      unsigned short* dp = dst + (size_t)d * 1024 + r0 + g * 16;
      *(ushort8*)dp = o0;
      *(ushort8*)(dp + 8) = o1;
      __syncthreads();
    }
  } else {
    bid -= 4608;
    int z = bid >> 9, rem = bid & 511;
    int by = rem >> 4, bx = rem & 15;
    int r0 = by * 64, c0 = bx * 64;     // r0: k (FF), c0: n (DM)
    const float* src0 = (z < 8) ? We2 + (size_t)z * FF * DM : Ws2;
    unsigned short* dst = wb2 + (size_t)z * 1024 * 2048;
    const float* src = src0 + (size_t)(r0 + r) * DM + c0;
#pragma unroll
    for (int i = 0; i < 4; i++)
      *(f32x4*)&tile[r][i * 16 + q * 4] = *(const f32x4*)(src + i * 16 + q * 4);
    __syncthreads();
    ushort8 o0, o1;
#pragma unroll
    for (int j = 0; j < 8; j++) o0[j] = f2bf(tile[g * 16 + j][nn]);
#pragma unroll
    for (int j = 0; j < 8; j++) o1[j] = f2bf(tile[g * 16 + 8 + j][nn]);
    unsigned short* dp = dst + (size_t)(c0 + nn) * 2048 + r0 + g * 16;
    *(ushort8*)dp = o0;
    *(ushort8*)(dp + 8) = o1;
  }
}

// ---------------- 256x256 8-phase GEMM, BK=64, 8 waves, counted vmcnt, optional split-K ----
// (R5/R10 schedule verbatim — verified race-free; B read once per K-tile at q0.)
// KSP>1: blockIdx.z packs (ks, e): e = z%9, ks = z/9. Block computes K-slice
// [ks*K/KSP, (ks+1)*K/KSP) — NTL = K/64/KSP tiles, same calendar (counts NT-independent),
// writes bf16 partial ks: partials 0..2 overlay wb13 (exact fit), partial 3 = old contrib.
//   P1: B1h1(t1)  P2: A1h0(t1)  P3: A1h1(t1)  P4: B0h0(t+2) + VMWAIT(2)
//   P5: B0h1(t+2) P6: A0h0(t+2) P7: A0h1(t+2) P8: B1h0(t+3) + VMWAIT(2)
template <bool G13, int K, int KSP, int NBROW>
__global__ __launch_bounds__(512, 2) void k_gemm(
    const unsigned short* __restrict__ A, const unsigned short* __restrict__ B,
    unsigned short* __restrict__ Hout, unsigned short* __restrict__ Cout,
    unsigned short* __restrict__ Pw,
    const int* __restrict__ slot_token, const int* __restrict__ offs,
    const int* __restrict__ counts) {
  __shared__ unsigned short lds[2][2][2][8192];   // [dbuf][A=0/B=1][half][128*64] = 128 KiB
  const int NTL = K / 64 / KSP;                   // tiles in this block's K-slice (even)

  int zz = blockIdx.z;
  int e = zz % 9, ks = zz / 9;
  const int KB = ks * NTL;                        // K-tile base of this slice
  int seg, cnt;
  if (e == 8) { seg = 8192; cnt = 4096; }
  else        { seg = offs[e]; cnt = counts[e]; }
  int m0 = blockIdx.y * 256;
  if (m0 >= cnt) return;
  int bn = blockIdx.x;

  int tid = threadIdx.x, lane = tid & 63, w = tid >> 6;

  int srcslot = (((tid & 7) ^ ((tid >> 3) & 7)) << 4);
  const char* aptr[2][2];
  const char* bptr[2][2];
#pragma unroll
  for (int half = 0; half < 2; half++)
#pragma unroll
    for (int j = 0; j < 2; j++) {
      int rl = half * 128 + j * 64 + (tid >> 3);
      int r = m0 + rl; if (r > cnt - 1) r = cnt - 1;
      long tok;
      if (G13) tok = (e == 8) ? (long)r : (long)slot_token[seg + r];
      else     tok = (long)(seg + r);
      aptr[half][j] = (const char*)A + ((size_t)tok * K) * 2 + srcslot;
      int br = bn * 256 + rl;
      bptr[half][j] = (const char*)B + (((size_t)e * NBROW + br) * K) * 2 + srcslot;
    }

#define STG(b, op, half, kt) do {                                                \
    const char* _p0 = (op ? bptr : aptr)[half][0] + (size_t)(KB + (kt)) * 128;   \
    const char* _p1 = (op ? bptr : aptr)[half][1] + (size_t)(KB + (kt)) * 128;   \
    async16(_p0, &lds[b][op][half][(size_t)w * 512]);                            \
    async16(_p1, &lds[b][op][half][4096 + (size_t)w * 512]);                     \
  } while (0)

  int wr = w >> 2, wc = w & 3, wch = wc >> 1;
  int s0 = (((0 + (lane >> 4)) ^ (lane & 7)) << 4);
  int s1 = (((4 + (lane >> 4)) ^ (lane & 7)) << 4);

  f32x4 acc[8][4];
#pragma unroll
  for (int i = 0; i < 8; i++)
#pragma unroll
    for (int j = 0; j < 4; j++) acc[i][j] = (f32x4){0.f, 0.f, 0.f, 0.f};

  short8 Af[2][2], Bf[4][2];

#define DO_PHASE(LA, LB, qq, STG_STMT, WAIT_STMT) do {                        \
    if (qq == 0) {                                                            \
      _Pragma("unroll") for (int nf = 0; nf < 4; nf++) {                      \
        int rb = ((wc & 1) * 64 + nf * 16 + (lane & 15)) * 128;               \
        Bf[nf][0] = *(const short8*)((LB) + rb + s0);                         \
        Bf[nf][1] = *(const short8*)((LB) + rb + s1);                         \
      }                                                                       \
    }                                                                         \
    _Pragma("unroll") for (int m2 = 0; m2 < 2; m2++) {                        \
      int ra = (((qq) * 2 + m2) * 16 + (lane & 15)) * 128;                    \
      Af[m2][0] = *(const short8*)((LA) + ra + s0);                           \
      Af[m2][1] = *(const short8*)((LA) + ra + s1);                           \
    }                                                                         \
    STG_STMT;                                                                 \
    BAR();                                                                    \
    LGKM0();                                                                  \
    SCHED0();                                                                 \
    __builtin_amdgcn_s_setprio(1);                                            \
    _Pragma("unroll") for (int m2 = 0; m2 < 2; m2++)                          \
      _Pragma("unroll") for (int nf = 0; nf < 4; nf++) {                      \
        acc[(qq) * 2 + m2][nf] = __builtin_amdgcn_mfma_f32_16x16x32_bf16(     \
            Af[m2][0], Bf[nf][0], acc[(qq) * 2 + m2][nf], 0, 0, 0);           \
        acc[(qq) * 2 + m2][nf] = __builtin_amdgcn_mfma_f32_16x16x32_bf16(     \
            Af[m2][1], Bf[nf][1], acc[(qq) * 2 + m2][nf], 0, 0, 0);           \
      }                                                                       \
    __builtin_amdgcn_s_setprio(0);                                            \
    WAIT_STMT;                                                                \
    BAR();                                                                    \
  } while (0)

  // prologue: slice-tile0 (4 halves -> buf0) + B1h0 of slice-tile1
  STG(0, 1, 0, 0);
  STG(0, 1, 1, 0);
  STG(0, 0, 0, 0);
  STG(0, 0, 1, 0);
  STG(1, 1, 0, 1);
  VMWAIT(2);
  BAR();

  const char* LA0 = (const char*)&lds[0][0][wr][0];
  const char* LB0 = (const char*)&lds[0][1][wch][0];
  const char* LA1 = (const char*)&lds[1][0][wr][0];
  const char* LB1 = (const char*)&lds[1][1][wch][0];

  for (int it = 0; it < NTL / 2; ++it) {
    int t1 = 2 * it + 1;
    int n2 = (2 * it + 2 < NTL) ? 2 * it + 2 : NTL - 1;   // clamped over-stage at tail
    int n3 = (2 * it + 3 < NTL) ? 2 * it + 3 : NTL - 1;   // (lands in retired buffers, never read)
    DO_PHASE(LA0, LB0, 0, STG(1, 1, 1, t1), );              // P1
    DO_PHASE(LA0, LB0, 1, STG(1, 0, 0, t1), );              // P2
    DO_PHASE(LA0, LB0, 2, STG(1, 0, 1, t1), );              // P3
    DO_PHASE(LA0, LB0, 3, STG(0, 1, 0, n2), VMWAIT(2));     // P4
    DO_PHASE(LA1, LB1, 0, STG(0, 1, 1, n2), );              // P5
    DO_PHASE(LA1, LB1, 1, STG(0, 0, 0, n2), );              // P6
    DO_PHASE(LA1, LB1, 2, STG(0, 0, 1, n2), );              // P7
    DO_PHASE(LA1, LB1, 3, STG(1, 1, 0, n3), VMWAIT(2));     // P8
  }
  VMWAIT(0);
#undef DO_PHASE
#undef STG

  // ---------------- epilogue ----------------
  if (G13) {
#pragma unroll
    for (int mi = 0; mi < 8; mi++)
#pragma unroll
      for (int j = 0; j < 2; j++)
#pragma unroll
        for (int q = 0; q < 4; q++) {
          int rl = wr * 128 + mi * 16 + (lane >> 4) * 4 + q;
          if (m0 + rl < cnt) {
            float s1v = acc[mi][2 * j][q], s3v = acc[mi][2 * j + 1][q];
            float h = (s1v / (1.f + __expf(-s1v))) * s3v;
            int ffcol = (bn * 8 + wc * 2 + j) * 16 + (lane & 15);
            Hout[(size_t)(seg + m0 + rl) * 2048 + ffcol] = f2bf(h);
          }
        }
  } else {
    unsigned short* Cp = (ks < 3) ? (Pw + (size_t)ks * PARTROWS) : Cout;
#pragma unroll
    for (int mi = 0; mi < 8; mi++)
#pragma unroll
      for (int nf = 0; nf < 4; nf++)
#pragma unroll
        for (int q = 0; q < 4; q++) {
          int rl = wr * 128 + mi * 16 + (lane >> 4) * 4 + q;
          if (m0 + rl < cnt) {
            int col = bn * 256 + wc * 64 + nf * 16 + (lane & 15);
            Cp[(size_t)(seg + m0 + rl) * 1024 + col] = f2bf(acc[mi][nf][q]);
          }
        }
  }
}

// out[t] = ( Σks sh_ks[t] + w0·Σks c_ks[s0] + w1·Σks c_ks[s1] ) / 3   (all partials bf16)
__global__ void k_combine(float* __restrict__ out, const unsigned short* __restrict__ PW,
                          const unsigned short* __restrict__ PC,
                          const int* __restrict__ token_slot, const float* __restrict__ topkw) {
  int t = blockIdx.x;
  int c = threadIdx.x * 4;
  int s0 = token_slot[t * 2 + 0], s1 = token_slot[t * 2 + 1];
  float w0 = topkw[t * 2 + 0], w1 = topkw[t * 2 + 1];
  f32x4 sum = (f32x4){0.f, 0.f, 0.f, 0.f};
#pragma unroll
  for (int ks = 0; ks < 4; ks++) {
    const unsigned short* P = (ks < 3) ? (PW + (size_t)ks * PARTROWS) : PC;
    u16x4 vs = *(const u16x4*)(P + (size_t)(8192 + t) * DM + c);
    u16x4 v0 = *(const u16x4*)(P + (size_t)s0 * DM + c);
    u16x4 v1 = *(const u16x4*)(P + (size_t)s1 * DM + c);
#pragma unroll
    for (int i = 0; i < 4; i++)
      sum[i] += bf2f(vs[i]) + w0 * bf2f(v0[i]) + w1 * bf2f(v1[i]);
  }
  float* po = out + (size_t)t * DM + c;
#pragma unroll
  for (int i = 0; i < 4; i++) sum[i] *= (1.f / 3.f);
  *(f32x4*)po = sum;
}

// ---------------- launcher ----------------
extern "C" void kernel_launch(void* const* d_in, const int* in_sizes, int n_in,
                              void* d_out, int out_size, void* d_ws, size_t ws_size,
                              hipStream_t stream) {
  const float* x   = (const float*)d_in[0];
  const float* Wg  = (const float*)d_in[1];
  const float* Ws1 = (const float*)d_in[2];
  const float* Ws3 = (const float*)d_in[3];
  const float* Ws2 = (const float*)d_in[4];
  const float* We1 = (const float*)d_in[5];
  const float* We3 = (const float*)d_in[6];
  const float* We2 = (const float*)d_in[7];
  float* out = (float*)d_out;

  if (ws_size < WS_NEEDED) return;

  char* w = (char*)d_ws;
  unsigned short* xb      = (unsigned short*)(w + OFF_XB);
  unsigned short* wb13    = (unsigned short*)(w + OFF_WB13);  // doubles as partials 0..2 after g13
  unsigned short* wb2     = (unsigned short*)(w + OFF_WB2);
  unsigned short* H       = (unsigned short*)(w + OFF_H);
  unsigned short* contrib = (unsigned short*)(w + OFF_CONTRIB);  // partial 3
  float* topkw            = (float*)(w + OFF_TOPKW);
  int* topki              = (int*)(w + OFF_TOPKI);
  int* slot_token         = (int*)(w + OFF_SLOTTOK);
  int* token_slot         = (int*)(w + OFF_TOKSLOT);
  int* counts             = (int*)(w + OFF_COUNTS);
  int* offs               = counts + 16;

  k_gatecvt<<<TTOK / 4, 256, 0, stream>>>(x, Wg, topkw, topki, xb);
  k_route<<<1, 1024, 0, stream>>>(topki, counts, offs, slot_token, token_slot);
  k_tw<<<9216, 256, 0, stream>>>(We1, We3, Ws1, Ws3, We2, Ws2, wb13, wb2);

  k_gemm<true, 1024, 1, 4096><<<dim3(16, 16, 9), 512, 0, stream>>>(
      xb, wb13, H, nullptr, nullptr, slot_token, offs, counts);
  k_gemm<false, 2048, 4, 1024><<<dim3(4, 16, 36), 512, 0, stream>>>(
      H, wb2, nullptr, contrib, wb13, slot_token, offs, counts);

  k_combine<<<TTOK, 256, 0, stream>>>(out, wb13, contrib, token_slot, topkw);
}